// Round 6
// baseline (308.344 us; speedup 1.0000x reference)
//
#include <hip/hip_runtime.h>

// DSR loss: R_t = sum_i w[t,i]*x[t,i];  A_t = c*A_{t-1} + eta*R_t (c=0.99),
// B_t likewise with R^2;  D_t from (A_prev,B_prev);  out = -sum(D)/B.
//
// R8: k1 re-plumbed onto the ONE untried load path: global_load_lds DMA
// (no VGPR return). Evidence: k1 pinned at 3.5 TB/s read across occupancy
// 30-70%, in-flight 2KB-192KB/wave, nt on/off -- the cap is the VGPR
// load-return path (fill = 6.9 TB/s write-only proves the fabric does more
// one-way; copy read-rate = 3.15 matches our cap). Stage 512-row w/x tiles
// (64 KB) to LDS with dwordx4 DMA, 2 blocks/CU overlap stage/compute,
// quarter-dots from LDS (2-way bank alias = free), shfl combine in the
// ORIGINAL bit-exact order ((d0+d1)+(d2+d3)). K3/K4/K5 logic unchanged,
// re-parameterized to CHUNK=512 (LPT=2).

#define D_ETA 0.01
#define D_C   (1.0 - D_ETA)
#define D_EPS 1e-8

constexpr int BLOCK  = 256;
constexpr int CHUNK  = 512;           // rows per block
constexpr int LPT    = CHUNK / BLOCK; // 2 rows per thread
constexpr int PASSES = CHUNK / 64;    // 8 passes of 64 rows per block
constexpr int LOADS_PER_WAVE = 8;     // 8 x 1KB per stream per wave (4 waves)

typedef float f32x4 __attribute__((ext_vector_type(4)));
typedef float f32x2 __attribute__((ext_vector_type(2)));

// direct global->LDS DMA, 16B per lane, wave-uniform LDS base + lane*16.
__device__ __forceinline__ void glds16(const void* gsrc, void* ldst) {
    __builtin_amdgcn_global_load_lds(
        (const __attribute__((address_space(1))) unsigned int*)gsrc,
        (__attribute__((address_space(3))) unsigned int*)(unsigned long long)ldst,
        16, 0, 0);
}

// Hillis-Steele inclusive scan over 256 affine transforms (m, sA, sB).
__device__ __forceinline__ void block_scan(double& m, double& sA, double& sB,
                                           double* mS, double* aS, double* bS) {
    int tid = threadIdx.x;
    mS[tid] = m; aS[tid] = sA; bS[tid] = sB;
    __syncthreads();
#pragma unroll
    for (int off = 1; off < BLOCK; off <<= 1) {
        double pm = 1.0, pa = 0.0, pb = 0.0;
        if (tid >= off) { pm = mS[tid - off]; pa = aS[tid - off]; pb = bS[tid - off]; }
        __syncthreads();
        if (tid >= off) {
            sA = m * pa + sA;
            sB = m * pb + sB;
            m  = pm * m;
        }
        mS[tid] = m; aS[tid] = sA; bS[tid] = sB;
        __syncthreads();
    }
}

// ---------------- K1'': DMA-staged dots + chunk aggregate ----------------
__global__ __launch_bounds__(BLOCK, 2) void k1_fused(
    const float* __restrict__ w, const float* __restrict__ x, int nrows,
    float* __restrict__ Rws,
    double* __restrict__ blkM, double* __restrict__ blkA, double* __restrict__ blkB)
{
    __shared__ float  wtile[CHUNK * 16];               // 32 KB
    __shared__ float  xtile[CHUNK * 16];               // 32 KB
    __shared__ float  R_l[CHUNK];                      // 2 KB
    __shared__ double mS[BLOCK], aS[BLOCK], bS[BLOCK]; // 6 KB

    const int tid  = threadIdx.x;
    const int b    = blockIdx.x;
    const long long base = (long long)b * CHUNK;
    const int q    = tid & 3;
    const int rsub = tid >> 2;
    const int wv   = tid >> 6;   // wave 0..3
    const int lane = tid & 63;

    const bool full = (base + CHUNK <= (long long)nrows);

    if (full) {
        // ---- stage: 64 KB via global_load_lds (no VGPR return path) ----
        // tile byte L*1024 + lane*16 maps linearly global->LDS.
        const char* wsrc = (const char*)w + (unsigned long long)base * 64;
        const char* xsrc = (const char*)x + (unsigned long long)base * 64;
#pragma unroll
        for (int i = 0; i < LOADS_PER_WAVE; ++i) {
            const int L = wv * LOADS_PER_WAVE + i;
            const unsigned long long goff =
                (unsigned long long)L * 1024ull + (unsigned long long)lane * 16ull;
            glds16(wsrc + goff, &wtile[L * 256]);
            glds16(xsrc + goff, &xtile[L * 256]);
        }
        __syncthreads();  // drains vmcnt(0): whole tile resident

        // ---- quarter-dots from LDS; original bit-exact combine order ----
#pragma unroll
        for (int p = 0; p < PASSES; ++p) {
            const int row = p * 64 + rsub;
            f32x4 a = *(const f32x4*)&wtile[row * 16 + q * 4]; // 2-way alias: free
            f32x4 c = *(const f32x4*)&xtile[row * 16 + q * 4];
            double d = (double)a.x * c.x + (double)a.y * c.y
                     + (double)a.z * c.z + (double)a.w * c.w;
            d += __shfl_xor(d, 1, 64);   // q0+q1 / q2+q3
            d += __shfl_xor(d, 2, 64);   // (d01)+(d23)
            if (q == 0) R_l[row] = (float)d;
        }
    } else {
        // tail chunk (last block): guarded direct-global path
        const f32x4* w4 = (const f32x4*)w;
        const f32x4* x4 = (const f32x4*)x;
        for (int p = 0; p < PASSES; ++p) {
            long long row = base + (long long)p * 64 + rsub;
            double d = 0.0;
            if (row < (long long)nrows) {
                long long f = row * 4 + q;
                f32x4 a = w4[f], c = x4[f];
                d = (double)a.x * c.x + (double)a.y * c.y
                  + (double)a.z * c.z + (double)a.w * c.w;
            }
            d += __shfl_xor(d, 1, 64);
            d += __shfl_xor(d, 2, 64);
            if (q == 0 && row < (long long)nrows) R_l[p * 64 + rsub] = (float)d;
        }
    }
    __syncthreads();

    // ---- Phase B: persist R, chunk affine aggregate ----
    long long g0 = base + (long long)tid * LPT;
    long long rem = (long long)nrows - g0;
    int len = rem >= LPT ? LPT : (rem > 0 ? (int)rem : 0);

    float rv[LPT];
#pragma unroll
    for (int r = 0; r < LPT; ++r) rv[r] = R_l[tid * LPT + r]; // 2-way alias: free

    if (len == LPT) {
        *(f32x2*)(Rws + g0) = (f32x2){rv[0], rv[1]};
    } else {
        for (int k = 0; k < len; ++k) Rws[g0 + k] = rv[k];
    }

    double m = 1.0, sA = 0.0, sB = 0.0;
    for (int k = 0; k < len; ++k) {
        double r = (double)rv[k];
        sA = D_C * sA + D_ETA * r;
        sB = D_C * sB + D_ETA * (r * r);
        m *= D_C;
    }
    block_scan(m, sA, sB, mS, aS, bS);
    if (tid == BLOCK - 1) {
        blkM[b] = m;
        blkA[b] = sA;
        blkB[b] = sB;
    }
}

// ---------------- fallback helpers (ws too small: recompute R) -------------
__device__ __forceinline__ float row_R(const float* __restrict__ w,
                                       const float* __restrict__ x,
                                       long long row) {
    const float4* w4 = (const float4*)(w + row * 16);
    const float4* x4 = (const float4*)(x + row * 16);
    double d0, d1, d2, d3;
    {
        float4 a = w4[0], b = x4[0];
        d0 = (double)a.x * b.x + (double)a.y * b.y
           + (double)a.z * b.z + (double)a.w * b.w;
    }
    {
        float4 a = w4[1], b = x4[1];
        d1 = (double)a.x * b.x + (double)a.y * b.y
           + (double)a.z * b.z + (double)a.w * b.w;
    }
    {
        float4 a = w4[2], b = x4[2];
        d2 = (double)a.x * b.x + (double)a.y * b.y
           + (double)a.z * b.z + (double)a.w * b.w;
    }
    {
        float4 a = w4[3], b = x4[3];
        d3 = (double)a.x * b.x + (double)a.y * b.y
           + (double)a.z * b.z + (double)a.w * b.w;
    }
    return (float)((d0 + d1) + (d2 + d3));
}

__device__ __forceinline__ int load_seg(const float* __restrict__ Rws,
                                        const float* __restrict__ w,
                                        const float* __restrict__ x,
                                        long long g0, int nrows, float* rv) {
    long long rem = (long long)nrows - g0;
    int len = rem >= LPT ? LPT : (rem > 0 ? (int)rem : 0);
    if (Rws) {
        if (len == LPT) {
            f32x2 u = __builtin_nontemporal_load((const f32x2*)(Rws + g0));
            rv[0] = u.x; rv[1] = u.y;
        } else {
            for (int k = 0; k < len; ++k) rv[k] = Rws[g0 + k];
        }
    } else {
        for (int k = 0; k < len; ++k) rv[k] = row_R(w, x, g0 + k);
    }
    return len;
}

// ---------------- K2 (fallback only): per-chunk affine aggregates ----------
__global__ __launch_bounds__(BLOCK) void k2_partials(
    const float* __restrict__ Rws,
    const float* __restrict__ w, const float* __restrict__ x, int nrows,
    double* __restrict__ blkM, double* __restrict__ blkA, double* __restrict__ blkB)
{
    __shared__ double mS[BLOCK], aS[BLOCK], bS[BLOCK];
    int tid = threadIdx.x;
    long long g0 = (long long)blockIdx.x * CHUNK + (long long)tid * LPT;
    float rv[LPT];
    int len = load_seg(Rws, w, x, g0, nrows, rv);

    double m = 1.0, sA = 0.0, sB = 0.0;
    for (int k = 0; k < len; ++k) {
        double r = (double)rv[k];
        sA = D_C * sA + D_ETA * r;
        sB = D_C * sB + D_ETA * (r * r);
        m *= D_C;
    }
    block_scan(m, sA, sB, mS, aS, bS);
    if (tid == BLOCK - 1) {
        blkM[blockIdx.x] = m;
        blkA[blockIdx.x] = sA;
        blkB[blockIdx.x] = sB;
    }
}

// ---------------- K3: scan of chunk aggregates (1 block) ----------------
__global__ __launch_bounds__(BLOCK) void k3_scan(
    int nb,
    const double* __restrict__ blkM, const double* __restrict__ blkA,
    const double* __restrict__ blkB,
    double* __restrict__ A0, double* __restrict__ B0)
{
    __shared__ double mS[BLOCK], aS[BLOCK], bS[BLOCK];
    int tid = threadIdx.x;
    int K = (nb + BLOCK - 1) / BLOCK;
    int g0 = tid * K;
    int g1 = g0 + K; if (g1 > nb) g1 = nb;

    double m = 1.0, sA = 0.0, sB = 0.0;
    for (int g = g0; g < g1; ++g) {
        double mg = blkM[g], ag = blkA[g], bg = blkB[g];
        sA = mg * sA + ag;
        sB = mg * sB + bg;
        m *= mg;
    }
    block_scan(m, sA, sB, mS, aS, bS);

    double em = 1.0, ea = 0.0, eb = 0.0;
    if (tid > 0) { em = mS[tid - 1]; ea = aS[tid - 1]; eb = bS[tid - 1]; }
    double A = ea;                 // em*0 + ea
    double B = em * D_EPS + eb;
    for (int g = g0; g < g1; ++g) {
        A0[g] = A; B0[g] = B;
        double mg = blkM[g], ag = blkA[g], bg = blkB[g];
        A = mg * A + ag;
        B = mg * B + bg;
    }
}

// ---------------- K4: replay + D sum ----------------
__global__ __launch_bounds__(BLOCK) void k4_dsum(
    const float* __restrict__ Rws,
    const float* __restrict__ w, const float* __restrict__ x, int nrows,
    const double* __restrict__ A0, const double* __restrict__ B0,
    double* __restrict__ bsum)
{
    __shared__ double mS[BLOCK], aS[BLOCK], bS[BLOCK];
    __shared__ double wsum[BLOCK / 64];
    int tid = threadIdx.x;
    long long g0 = (long long)blockIdx.x * CHUNK + (long long)tid * LPT;
    float rv[LPT];
    int len = load_seg(Rws, w, x, g0, nrows, rv);

    double m = 1.0, sA = 0.0, sB = 0.0;
    for (int k = 0; k < len; ++k) {
        double r = (double)rv[k];
        sA = D_C * sA + D_ETA * r;
        sB = D_C * sB + D_ETA * (r * r);
        m *= D_C;
    }
    block_scan(m, sA, sB, mS, aS, bS);

    double em = 1.0, ea = 0.0, eb = 0.0;
    if (tid > 0) { em = mS[tid - 1]; ea = aS[tid - 1]; eb = bS[tid - 1]; }
    double A = em * A0[blockIdx.x] + ea;
    double B = em * B0[blockIdx.x] + eb;

    double dsum = 0.0;
    for (int k = 0; k < len; ++k) {
        double r = (double)rv[k];
        double dA = D_ETA * (r - A);
        double dB = D_ETA * (r * r - B);
        double var = B - A * A;
        if (var < D_EPS) var = D_EPS;
        double denom = var * sqrt(var);
        dsum += (B * dA - 0.5 * A * dB) / denom;
        A += dA;
        B += dB;
    }

#pragma unroll
    for (int off = 32; off > 0; off >>= 1) dsum += __shfl_down(dsum, off, 64);
    if ((tid & 63) == 0) wsum[tid >> 6] = dsum;
    __syncthreads();
    if (tid == 0) bsum[blockIdx.x] = wsum[0] + wsum[1] + wsum[2] + wsum[3];
}

// ---------------- K5: final reduction ----------------
__global__ __launch_bounds__(BLOCK) void k5_final(
    const double* __restrict__ bsum, int nb, int nrows, float* __restrict__ out)
{
    __shared__ double sh[BLOCK / 64];
    int tid = threadIdx.x;
    double s = 0.0;
    for (int i = tid; i < nb; i += BLOCK) s += bsum[i];
#pragma unroll
    for (int off = 32; off > 0; off >>= 1) s += __shfl_down(s, off, 64);
    if ((tid & 63) == 0) sh[tid >> 6] = s;
    __syncthreads();
    if (tid == 0) out[0] = (float)(-(sh[0] + sh[1] + sh[2] + sh[3]) / (double)nrows);
}

extern "C" void kernel_launch(void* const* d_in, const int* in_sizes, int n_in,
                              void* d_out, int out_size, void* d_ws, size_t ws_size,
                              hipStream_t stream)
{
    const float* w = (const float*)d_in[0];
    const float* x = (const float*)d_in[1];
    int nrows = in_sizes[0] / 16;
    int nb  = (nrows + CHUNK - 1) / CHUNK;

    char* ws = (char*)d_ws;
    double* blkM = (double*)(ws + 64);
    double* blkA = blkM + nb;
    double* blkB = blkA + nb;
    double* A0   = blkB + nb;
    double* B0   = A0 + nb;
    double* bsum = B0 + nb;

    size_t off = 64 + (size_t)6 * nb * sizeof(double);
    off = (off + 255) & ~(size_t)255;
    float* Rws = nullptr;
    if (ws_size >= off + (size_t)nrows * sizeof(float))
        Rws = (float*)(ws + off);

    if (Rws) {
        // fused K1+K2: single pass over w,x via LDS-DMA; R persisted once
        k1_fused<<<nb, BLOCK, 0, stream>>>(w, x, nrows, Rws, blkM, blkA, blkB);
    } else {
        k2_partials<<<nb, BLOCK, 0, stream>>>(Rws, w, x, nrows, blkM, blkA, blkB);
    }
    k3_scan<<<1, BLOCK, 0, stream>>>(nb, blkM, blkA, blkB, A0, B0);
    k4_dsum<<<nb, BLOCK, 0, stream>>>(Rws, w, x, nrows, A0, B0, bsum);
    k5_final<<<1, BLOCK, 0, stream>>>(bsum, nb, nrows, (float*)d_out);
}

// Round 7
// 259.475 us; speedup vs baseline: 1.1883x; 1.1883x over previous
//
#include <hip/hip_runtime.h>

// DSR loss: R_t = sum_i w[t,i]*x[t,i];  A_t = c*A_{t-1} + eta*R_t (c=0.99),
// B_t likewise with R^2;  D_t from (A_prev,B_prev);  out = -sum(D)/B.
//
// R9: k1 = R7's best (nt loads, distance-4 rotating pipeline, shfl pair-
// combine, CHUNK1=1024) -- k1 is at the measured streaming-read wall
// (3.5-4 TB/s across VGPR/nt/LDS-DMA paths, occupancy 17-70%, depth 1-4).
// Pipeline shortened 4 -> 3 dispatches: k3 deleted; k4 (CHUNK4=2048) does
// its own predecessor-aggregate lookback (R3 Phase C pattern, absmax-0.0
// proven) before the replay. k5 unchanged.

#define D_ETA 0.01
#define D_C   (1.0 - D_ETA)
#define D_EPS 1e-8

constexpr int BLOCK   = 256;
constexpr int CHUNK1  = 1024;           // k1 rows per block
constexpr int LPT1    = CHUNK1 / BLOCK; // 4
constexpr int PASSES  = CHUNK1 / 64;    // 16
constexpr int CHUNK4  = 2048;           // k4 rows per block
constexpr int LPT4    = CHUNK4 / BLOCK; // 8

typedef float f32x4 __attribute__((ext_vector_type(4)));

// Hillis-Steele inclusive scan over 256 affine transforms (m, sA, sB).
__device__ __forceinline__ void block_scan(double& m, double& sA, double& sB,
                                           double* mS, double* aS, double* bS) {
    int tid = threadIdx.x;
    mS[tid] = m; aS[tid] = sA; bS[tid] = sB;
    __syncthreads();
#pragma unroll
    for (int off = 1; off < BLOCK; off <<= 1) {
        double pm = 1.0, pa = 0.0, pb = 0.0;
        if (tid >= off) { pm = mS[tid - off]; pa = aS[tid - off]; pb = bS[tid - off]; }
        __syncthreads();
        if (tid >= off) {
            sA = m * pa + sA;
            sB = m * pb + sB;
            m  = pm * m;
        }
        mS[tid] = m; aS[tid] = sA; bS[tid] = sB;
        __syncthreads();
    }
}

// ---------------- K1: dots + per-1024-chunk aggregate (R7 config) ----------
__global__ __launch_bounds__(BLOCK, 6) void k1_fused(
    const float* __restrict__ w, const float* __restrict__ x, int nrows,
    float* __restrict__ Rws,
    double* __restrict__ blkM, double* __restrict__ blkA, double* __restrict__ blkB)
{
    __shared__ double Qs[2][CHUNK1];                   // 16 KB, [pair][row]
    __shared__ double mS[BLOCK], aS[BLOCK], bS[BLOCK]; // 6 KB

    const int tid = threadIdx.x;
    const int b   = blockIdx.x;
    const long long base = (long long)b * CHUNK1;
    const int q    = tid & 3;
    const int rsub = tid >> 2;
    const f32x4* w4 = (const f32x4*)w;
    const f32x4* x4 = (const f32x4*)x;

    const bool full = (base + CHUNK1 <= (long long)nrows);

    if (full) {
        const long long f0 = base * 4 + tid;
        // distance-4 rotating pipeline: named registers, compile-time rotation
        f32x4 a0 = __builtin_nontemporal_load(&w4[f0]);
        f32x4 c0 = __builtin_nontemporal_load(&x4[f0]);
        f32x4 a1 = __builtin_nontemporal_load(&w4[f0 + 256]);
        f32x4 c1 = __builtin_nontemporal_load(&x4[f0 + 256]);
        f32x4 a2 = __builtin_nontemporal_load(&w4[f0 + 512]);
        f32x4 c2 = __builtin_nontemporal_load(&x4[f0 + 512]);
        f32x4 a3 = __builtin_nontemporal_load(&w4[f0 + 768]);
        f32x4 c3 = __builtin_nontemporal_load(&x4[f0 + 768]);
#pragma unroll
        for (int p = 0; p < PASSES; ++p) {
            f32x4 an = (f32x4)(0.f);
            f32x4 cn = (f32x4)(0.f);
            if (p + 4 < PASSES) {             // compile-time after unroll
                an = __builtin_nontemporal_load(&w4[f0 + (long long)(p + 4) * 256]);
                cn = __builtin_nontemporal_load(&x4[f0 + (long long)(p + 4) * 256]);
            }
            __builtin_amdgcn_sched_barrier(0); // prefetch issued before consume
            double d = (double)a0.x * c0.x + (double)a0.y * c0.y
                     + (double)a0.z * c0.z + (double)a0.w * c0.w;
            d += __shfl_xor(d, 1, 64);         // d01 on q=0/1, d23 on q=2/3
            if ((q & 1) == 0)
                Qs[q >> 1][p * 64 + rsub] = d; // fire-and-forget ds_write_b64
            a0 = a1; c0 = c1;
            a1 = a2; c1 = c2;
            a2 = a3; c2 = c3;
            a3 = an; c3 = cn;
        }
    } else {
        // tail chunk: guarded loads, shfl stays wave-uniform
        for (int p = 0; p < PASSES; ++p) {
            long long row = base + (long long)p * 64 + rsub;
            double d = 0.0;
            if (row < (long long)nrows) {
                long long f = row * 4 + q;
                f32x4 a = w4[f], c = x4[f];
                d = (double)a.x * c.x + (double)a.y * c.y
                  + (double)a.z * c.z + (double)a.w * c.w;
            }
            d += __shfl_xor(d, 1, 64);
            if ((q & 1) == 0 && row < (long long)nrows)
                Qs[q >> 1][p * 64 + rsub] = d;
        }
    }
    __syncthreads();

    // ---- combine pairs, persist R, chunk aggregate ----
    long long g0 = base + (long long)tid * LPT1;
    long long rem = (long long)nrows - g0;
    int len = rem >= LPT1 ? LPT1 : (rem > 0 ? (int)rem : 0);

    float rv[LPT1];
#pragma unroll
    for (int r = 0; r < LPT1; ++r) {
        int lr = tid * LPT1 + r;
        rv[r] = (float)(Qs[0][lr] + Qs[1][lr]); // (d0+d1)+(d2+d3) order
    }

    if (len == LPT1) {
        *(float4*)(Rws + g0) = make_float4(rv[0], rv[1], rv[2], rv[3]);
    } else {
        for (int k = 0; k < len; ++k) Rws[g0 + k] = rv[k];
    }

    double m = 1.0, sA = 0.0, sB = 0.0;
    for (int k = 0; k < len; ++k) {
        double r = (double)rv[k];
        sA = D_C * sA + D_ETA * r;
        sB = D_C * sB + D_ETA * (r * r);
        m *= D_C;
    }
    block_scan(m, sA, sB, mS, aS, bS);
    if (tid == BLOCK - 1) {
        blkM[b] = m;
        blkA[b] = sA;
        blkB[b] = sB;
    }
}

// ---------------- fallback helpers (ws too small: recompute R) -------------
__device__ __forceinline__ float row_R(const float* __restrict__ w,
                                       const float* __restrict__ x,
                                       long long row) {
    const float4* w4 = (const float4*)(w + row * 16);
    const float4* x4 = (const float4*)(x + row * 16);
    double d0, d1, d2, d3;
    {
        float4 a = w4[0], b = x4[0];
        d0 = (double)a.x * b.x + (double)a.y * b.y
           + (double)a.z * b.z + (double)a.w * b.w;
    }
    {
        float4 a = w4[1], b = x4[1];
        d1 = (double)a.x * b.x + (double)a.y * b.y
           + (double)a.z * b.z + (double)a.w * b.w;
    }
    {
        float4 a = w4[2], b = x4[2];
        d2 = (double)a.x * b.x + (double)a.y * b.y
           + (double)a.z * b.z + (double)a.w * b.w;
    }
    {
        float4 a = w4[3], b = x4[3];
        d3 = (double)a.x * b.x + (double)a.y * b.y
           + (double)a.z * b.z + (double)a.w * b.w;
    }
    return (float)((d0 + d1) + (d2 + d3));
}

// ---------------- K2 (fallback only): per-1024-chunk aggregates ------------
__global__ __launch_bounds__(BLOCK) void k2_partials(
    const float* __restrict__ w, const float* __restrict__ x, int nrows,
    double* __restrict__ blkM, double* __restrict__ blkA, double* __restrict__ blkB)
{
    __shared__ double mS[BLOCK], aS[BLOCK], bS[BLOCK];
    int tid = threadIdx.x;
    long long g0 = (long long)blockIdx.x * CHUNK1 + (long long)tid * LPT1;
    long long rem = (long long)nrows - g0;
    int len = rem >= LPT1 ? LPT1 : (rem > 0 ? (int)rem : 0);

    double m = 1.0, sA = 0.0, sB = 0.0;
    for (int k = 0; k < len; ++k) {
        double r = (double)row_R(w, x, g0 + k);
        sA = D_C * sA + D_ETA * r;
        sB = D_C * sB + D_ETA * (r * r);
        m *= D_C;
    }
    block_scan(m, sA, sB, mS, aS, bS);
    if (tid == BLOCK - 1) {
        blkM[blockIdx.x] = m;
        blkA[blockIdx.x] = sA;
        blkB[blockIdx.x] = sB;
    }
}

// ---------------- K4: lookback prefix + replay + D sum ----------------
// Block b covers rows [b*2048, (b+1)*2048). Its entry state comes from
// composing the first 2b per-1024 aggregates (R3 Phase C pattern: tid-strided
// compose + block_scan; identity-padded threads make the [BLOCK-1] entry the
// total regardless of H<BLOCK).
__global__ __launch_bounds__(BLOCK) void k4_dsum(
    const float* __restrict__ Rws,
    const float* __restrict__ w, const float* __restrict__ x, int nrows,
    const double* __restrict__ blkM, const double* __restrict__ blkA,
    const double* __restrict__ blkB,
    double* __restrict__ bsum)
{
    __shared__ double mS[BLOCK], aS[BLOCK], bS[BLOCK];
    __shared__ double wsum[BLOCK / 64];
    const int tid = threadIdx.x;
    const int b   = blockIdx.x;

    // ---- phase 1: entry state via aggregate lookback ----
    double Astart, Bstart;
    {
        const int H = 2 * b;                     // per-1024 aggregates before us
        const int K = (H + BLOCK - 1) / BLOCK;   // 0 when b==0
        double cm = 1.0, ca = 0.0, cb = 0.0;
        int s0 = tid * K;
        int s1 = s0 + K; if (s1 > H) s1 = H;
        for (int g = s0; g < s1; ++g) {
            double mg = blkM[g], ag = blkA[g], bg = blkB[g];
            ca = mg * ca + ag;
            cb = mg * cb + bg;
            cm *= mg;
        }
        block_scan(cm, ca, cb, mS, aS, bS);
        double M  = mS[BLOCK - 1];
        double SA = aS[BLOCK - 1];
        double SB = bS[BLOCK - 1];
        Astart = SA;                 // M*0 + SA
        Bstart = M * D_EPS + SB;
    }
    __syncthreads();                 // mS/aS/bS reused below

    // ---- phase 2: load this thread's R segment ----
    long long g0 = (long long)b * CHUNK4 + (long long)tid * LPT4;
    long long rem = (long long)nrows - g0;
    int len = rem >= LPT4 ? LPT4 : (rem > 0 ? (int)rem : 0);

    float rv[LPT4];
    if (Rws) {
        if (len == LPT4) {
            f32x4 u = __builtin_nontemporal_load((const f32x4*)(Rws + g0));
            f32x4 v = __builtin_nontemporal_load((const f32x4*)(Rws + g0 + 4));
            rv[0]=u.x; rv[1]=u.y; rv[2]=u.z; rv[3]=u.w;
            rv[4]=v.x; rv[5]=v.y; rv[6]=v.z; rv[7]=v.w;
        } else {
            for (int k = 0; k < len; ++k) rv[k] = Rws[g0 + k];
        }
    } else {
        for (int k = 0; k < len; ++k) rv[k] = row_R(w, x, g0 + k);
    }

    // ---- phase 3: thread aggregate + block scan -> per-thread entry ----
    double m = 1.0, sA = 0.0, sB = 0.0;
    for (int k = 0; k < len; ++k) {
        double r = (double)rv[k];
        sA = D_C * sA + D_ETA * r;
        sB = D_C * sB + D_ETA * (r * r);
        m *= D_C;
    }
    block_scan(m, sA, sB, mS, aS, bS);

    double em = 1.0, ea = 0.0, eb = 0.0;
    if (tid > 0) { em = mS[tid - 1]; ea = aS[tid - 1]; eb = bS[tid - 1]; }
    double A = em * Astart + ea;
    double B = em * Bstart + eb;

    // ---- phase 4: replay + D sum ----
    double dsum = 0.0;
    for (int k = 0; k < len; ++k) {
        double r = (double)rv[k];
        double dA = D_ETA * (r - A);
        double dB = D_ETA * (r * r - B);
        double var = B - A * A;
        if (var < D_EPS) var = D_EPS;
        double denom = var * sqrt(var);
        dsum += (B * dA - 0.5 * A * dB) / denom;
        A += dA;
        B += dB;
    }

#pragma unroll
    for (int off = 32; off > 0; off >>= 1) dsum += __shfl_down(dsum, off, 64);
    if ((tid & 63) == 0) wsum[tid >> 6] = dsum;
    __syncthreads();
    if (tid == 0) bsum[b] = wsum[0] + wsum[1] + wsum[2] + wsum[3];
}

// ---------------- K5: final reduction ----------------
__global__ __launch_bounds__(BLOCK) void k5_final(
    const double* __restrict__ bsum, int nb, int nrows, float* __restrict__ out)
{
    __shared__ double sh[BLOCK / 64];
    int tid = threadIdx.x;
    double s = 0.0;
    for (int i = tid; i < nb; i += BLOCK) s += bsum[i];
#pragma unroll
    for (int off = 32; off > 0; off >>= 1) s += __shfl_down(s, off, 64);
    if ((tid & 63) == 0) sh[tid >> 6] = s;
    __syncthreads();
    if (tid == 0) out[0] = (float)(-(sh[0] + sh[1] + sh[2] + sh[3]) / (double)nrows);
}

extern "C" void kernel_launch(void* const* d_in, const int* in_sizes, int n_in,
                              void* d_out, int out_size, void* d_ws, size_t ws_size,
                              hipStream_t stream)
{
    const float* w = (const float*)d_in[0];
    const float* x = (const float*)d_in[1];
    int nrows = in_sizes[0] / 16;
    int nb1 = (nrows + CHUNK1 - 1) / CHUNK1;  // k1/k2 aggregate count
    int nb4 = (nrows + CHUNK4 - 1) / CHUNK4;  // k4 block count

    char* ws = (char*)d_ws;
    double* blkM = (double*)(ws + 64);
    double* blkA = blkM + nb1;
    double* blkB = blkA + nb1;
    double* bsum = blkB + nb1;

    size_t off = 64 + ((size_t)3 * nb1 + nb4) * sizeof(double);
    off = (off + 255) & ~(size_t)255;
    float* Rws = nullptr;
    if (ws_size >= off + (size_t)nrows * sizeof(float))
        Rws = (float*)(ws + off);

    if (Rws) {
        // fused dots + per-1024 aggregates; R persisted once
        k1_fused<<<nb1, BLOCK, 0, stream>>>(w, x, nrows, Rws, blkM, blkA, blkB);
    } else {
        k2_partials<<<nb1, BLOCK, 0, stream>>>(w, x, nrows, blkM, blkA, blkB);
    }
    k4_dsum<<<nb4, BLOCK, 0, stream>>>(Rws, w, x, nrows, blkM, blkA, blkB, bsum);
    k5_final<<<1, BLOCK, 0, stream>>>(bsum, nb4, nrows, (float*)d_out);
}